// Round 7
// baseline (509.282 us; speedup 1.0000x reference)
//
#include <hip/hip_runtime.h>
#include <stdint.h>

#define ALPHA 0.2f
#define LOG2E 1.44269504088896340736f

typedef __attribute__((ext_vector_type(8))) short bf16x8;
typedef __attribute__((ext_vector_type(4))) float f32x4;

__device__ __forceinline__ unsigned short f2bf(float f) {
    unsigned u = __builtin_bit_cast(unsigned, f);
    u += 0x7fffu + ((u >> 16) & 1u);
    return (unsigned short)(u >> 16);
}
__device__ __forceinline__ float bf2f(unsigned short h) {
    unsigned u = ((unsigned)h) << 16;
    return __builtin_bit_cast(float, u);
}
__device__ __forceinline__ unsigned f2ord(float f) {
    unsigned b = __builtin_bit_cast(unsigned, f);
    return (b & 0x80000000u) ? ~b : (b | 0x80000000u);
}
__device__ __forceinline__ float ord2f(unsigned k) {
    unsigned b = (k & 0x80000000u) ? (k & 0x7fffffffu) : ~k;
    return __builtin_bit_cast(float, b);
}

// ---------------------------------------------------------------------------
// Kernel 0: pure-streaming bit-pack of adj. Copy-shaped: 8 independent
// coalesced int4 loads into registers FIRST (8 KB in flight per wave), then
// nibble-pack via LDS, one coalesced uint store per thread.
// Linear layout: bit b of adjU[w] = adj[w*32 + b].
__global__ __launch_bounds__(256) void gat_pack(
    const int* __restrict__ adj, unsigned* __restrict__ adjU)
{
    __shared__ unsigned char nib[2048];
    const int tid = threadIdx.x;
    const size_t base = (size_t)blockIdx.x * 8192;   // int index

    int4 v[8];
    #pragma unroll
    for (int it = 0; it < 8; ++it)
        v[it] = *(const int4*)&adj[base + it * 1024 + tid * 4];
    #pragma unroll
    for (int it = 0; it < 8; ++it)
        nib[it * 256 + tid] =
            (unsigned char)(v[it].x + (v[it].y << 1) + (v[it].z << 2) + (v[it].w << 3));
    __syncthreads();

    const uint2 u = *(const uint2*)&nib[tid * 8];
    const unsigned w = (u.x & 0xFu)          | ((u.x >> 4) & 0xF0u)
                     | ((u.x >> 8) & 0xF00u) | ((u.x >> 12) & 0xF000u)
                     | ((u.y << 16) & 0xF0000u)  | ((u.y << 12) & 0xF00000u)
                     | ((u.y << 8) & 0xF000000u) | ((u.y << 4) & 0xF0000000u);
    adjU[blockIdx.x * 256 + tid] = w;
}

// ---------------------------------------------------------------------------
// Kernel 1: hPart[ks] = input[:, ks*128:(ks+1)*128] @ W[ks*128:...], fp32.
__global__ __launch_bounds__(256) void gat_h(
    const float* __restrict__ input, const float* __restrict__ W,
    float* __restrict__ hPart)
{
    __shared__ float x_lds[16 * 128];
    const int tid = threadIdx.x;
    const int i0  = (blockIdx.x >> 2) * 16;
    const int ks  = blockIdx.x & 3;
    const int k0  = ks * 128;

    {
        const int r  = tid >> 4;
        const int jc = (tid & 15) * 8;
        const float* src = input + (size_t)(i0 + r) * 512 + k0 + jc;
        *(f32x4*)&x_lds[r * 128 + jc]     = *(const f32x4*)src;
        *(f32x4*)&x_lds[r * 128 + jc + 4] = *(const f32x4*)(src + 4);
    }
    __syncthreads();

    const int c = tid & 63;
    const int w = tid >> 6;
    float acc[4] = {0.f, 0.f, 0.f, 0.f};
    const float* Wc = W + (size_t)k0 * 64 + c;
    #pragma unroll 4
    for (int kk = 0; kk < 128; kk += 4) {
        const float w0 = Wc[(kk+0)*64], w1 = Wc[(kk+1)*64];
        const float w2 = Wc[(kk+2)*64], w3 = Wc[(kk+3)*64];
        #pragma unroll
        for (int ri = 0; ri < 4; ++ri) {
            const f32x4 x = *(const f32x4*)&x_lds[(w + 4*ri) * 128 + kk];
            acc[ri] += x.x * w0 + x.y * w1 + x.z * w2 + x.w * w3;
        }
    }
    #pragma unroll
    for (int ri = 0; ri < 4; ++ri)
        hPart[((size_t)ks * 8192 + i0 + w + 4*ri) * 64 + c] = acc[ri];
}

// ---------------------------------------------------------------------------
// Kernel 2: sum 4 h-slabs; attL, ER=exp(attR), ER2=exp(0.2*attR), R=max(attR),
// hPack (MFMA-B-fragment-major bf16 h^T).
__global__ __launch_bounds__(256) void gat_aux(
    const float* __restrict__ hPart, const float* __restrict__ a,
    float* __restrict__ attL, float* __restrict__ ERt, float* __restrict__ ER2t,
    unsigned short* __restrict__ hPack, unsigned* __restrict__ wsR)
{
    __shared__ float hl[32 * 64];
    __shared__ unsigned rmax;
    const int tid = threadIdx.x;
    const int j0  = blockIdx.x * 32;
    if (tid == 0) rmax = 0u;

    {
        const size_t base = (size_t)j0 * 64 + tid * 8;
        f32x4 s0 = *(const f32x4*)&hPart[base];
        f32x4 s1 = *(const f32x4*)&hPart[base + 4];
        #pragma unroll
        for (int ks = 1; ks < 4; ++ks) {
            const size_t o = (size_t)ks * 524288 + base;
            const f32x4 u0 = *(const f32x4*)&hPart[o];
            const f32x4 u1 = *(const f32x4*)&hPart[o + 4];
            s0.x += u0.x; s0.y += u0.y; s0.z += u0.z; s0.w += u0.w;
            s1.x += u1.x; s1.y += u1.y; s1.z += u1.z; s1.w += u1.w;
        }
        *(f32x4*)&hl[tid * 8]     = s0;
        *(f32x4*)&hl[tid * 8 + 4] = s1;
    }
    __syncthreads();

    {
        const int row = tid >> 3;
        const int cs  = (tid & 7) * 8;
        float pL = 0.f, pR = 0.f;
        #pragma unroll
        for (int u = 0; u < 8; ++u) {
            const float hv = hl[row * 64 + cs + u];
            pL += hv * a[cs + u];
            pR += hv * a[64 + cs + u];
        }
        pL += __shfl_xor(pL, 1, 64); pR += __shfl_xor(pR, 1, 64);
        pL += __shfl_xor(pL, 2, 64); pR += __shfl_xor(pR, 2, 64);
        pL += __shfl_xor(pL, 4, 64); pR += __shfl_xor(pR, 4, 64);
        if ((tid & 7) == 0) {
            attL[j0 + row] = pL;
            ERt [j0 + row] = __builtin_amdgcn_exp2f(pR * LOG2E);
            ER2t[j0 + row] = __builtin_amdgcn_exp2f(ALPHA * pR * LOG2E);
            atomicMax(&rmax, f2ord(pR));
        }
    }

    {
        const int g = tid >> 6;
        const int l = tid & 63;
        const int m = l & 15;
        const int q = l >> 4;
        bf16x8 v;
        #pragma unroll
        for (int u = 0; u < 8; ++u)
            v[u] = (short)f2bf(hl[(q * 8 + u) * 64 + g * 16 + m]);
        *(bf16x8*)&hPack[(size_t)(blockIdx.x * 4 + g) * 512 + l * 8] = v;
    }

    __syncthreads();
    if (tid == 0) atomicMax(wsR, rmax);
}

// ---------------------------------------------------------------------------
// Kernel 3: attn. Masks come from adjU (L2-resident 8 MB): word w=(i*256+jc)
// holds bits (q*8+u) for j=jc*32+q*8+u. Each wave preloads its 16 words as
// one int4/lane, redistributes per step with one __shfl. p = max(EL*ER_j,
// EL2*ER2_j) (exp factored out; exp monotone). Per-q4 partial slabs.
__global__ __launch_bounds__(256, 8) void gat_attn(
    const unsigned* __restrict__ adjU,
    const float* __restrict__ attL, const float* __restrict__ ERt,
    const float* __restrict__ ER2t,
    const unsigned short* __restrict__ hPack, const unsigned* __restrict__ wsR,
    float* __restrict__ pOut, float* __restrict__ lPart)
{
    __shared__ float accf[4096];
    __shared__ float l_lds[64];
    const int tid  = threadIdx.x;
    const int lane = tid & 63;
    const int wq   = tid >> 6;
    const int m    = lane & 15;
    const int quad = lane >> 4;
    const int ti   = blockIdx.x >> 2;
    const int q4   = blockIdx.x & 3;
    const int i0   = ti * 16;
    const int jc0  = q4 * 64 + wq * 16;

    // preload this wave's 16 mask words: lane (m,q) holds words jc0+q*4..+4 of row m
    const int4 maskv = *(const int4*)&adjU[(size_t)(i0 + m) * 256 + jc0 + quad * 4];
    const unsigned mk[4] = { (unsigned)maskv.x, (unsigned)maskv.y,
                             (unsigned)maskv.z, (unsigned)maskv.w };

    const float R   = ord2f(*wsR);
    const float a_l = attL[i0 + m];
    const float t0  = a_l + R;
    const float M   = fmaxf(t0, ALPHA * t0);   // row upper bound (lrelu monotone)
    const float mc  = M * LOG2E;
    const float EL  = __builtin_amdgcn_exp2f(__builtin_fmaf(a_l, LOG2E, -mc));
    const float EL2 = __builtin_amdgcn_exp2f(__builtin_fmaf(ALPHA * a_l, LOG2E, -mc));

    const float*          er_p  = ERt  + jc0 * 32 + quad * 8;
    const float*          er2_p = ER2t + jc0 * 32 + quad * 8;
    const unsigned short* hp_p  = hPack + (size_t)jc0 * 4 * 512 + lane * 8;

    f32x4 acc[4];
    #pragma unroll
    for (int g = 0; g < 4; ++g) acc[g] = (f32x4){0.f, 0.f, 0.f, 0.f};
    float lsum = 0.f;

    #pragma unroll
    for (int s = 0; s < 16; ++s) {
        // word (m, jc0+s) lives in lane (m, s>>2) slot (s&3); one shuffle
        const unsigned wmask = (unsigned)__shfl((int)mk[s & 3], m + (s >> 2) * 16, 64);
        const unsigned bits  = (wmask >> (quad * 8)) & 0xffu;

        const f32x4 e0 = *(const f32x4*)(er_p  + s * 32);
        const f32x4 e1 = *(const f32x4*)(er_p  + s * 32 + 4);
        const f32x4 f0 = *(const f32x4*)(er2_p + s * 32);
        const f32x4 f1 = *(const f32x4*)(er2_p + s * 32 + 4);
        bf16x8 B[4];
        #pragma unroll
        for (int g = 0; g < 4; ++g)
            B[g] = *(const bf16x8*)(hp_p + (size_t)(s * 4 + g) * 512);

        const float ev[8] = { e0.x, e0.y, e0.z, e0.w, e1.x, e1.y, e1.z, e1.w };
        const float fv[8] = { f0.x, f0.y, f0.z, f0.w, f1.x, f1.y, f1.z, f1.w };
        bf16x8 af;
        #pragma unroll
        for (int u = 0; u < 8; ++u) {
            const float p  = fmaxf(EL * ev[u], EL2 * fv[u]);  // = exp(lrelu(s)-M)
            const float pv = (bits & (1u << u)) ? p : 0.0f;   // mask
            const unsigned short pb = f2bf(pv);
            af[u] = (short)pb;
            lsum += bf2f(pb);   // denominator from the SAME rounded weights
        }
        #pragma unroll
        for (int g = 0; g < 4; ++g)
            acc[g] = __builtin_amdgcn_mfma_f32_16x16x32_bf16(af, B[g], acc[g], 0, 0, 0);
    }

    // reduce l across the 4 k-quads
    lsum += __shfl_xor(lsum, 16, 64);
    lsum += __shfl_xor(lsum, 32, 64);
    if (lane < 16) l_lds[wq * 16 + lane] = lsum;
    #pragma unroll
    for (int g = 0; g < 4; ++g)
        *(f32x4*)&accf[(wq * 64 + lane) * 16 + g * 4] = acc[g];
    __syncthreads();

    // combine 4 waves, write partial numerator slab (no atomics)
    #pragma unroll
    for (int q = 0; q < 4; ++q) {
        const int e      = tid + q * 256;
        const int lane_e = e >> 4;
        const int k16    = e & 15;
        float s = 0.f;
        #pragma unroll
        for (int ww = 0; ww < 4; ++ww) s += accf[(ww * 64 + lane_e) * 16 + k16];
        const int row = (lane_e >> 4) * 4 + (k16 & 3);   // C/D: row = quad*4+reg
        const int col = (k16 >> 2) * 16 + (lane_e & 15); // C/D: col = lane&15 per n-group
        pOut[((size_t)q4 * 8192 + i0 + row) * 64 + col] = s;
    }
    if (tid < 16) {
        lPart[q4 * 8192 + i0 + tid] =
            l_lds[tid] + l_lds[16 + tid] + l_lds[32 + tid] + l_lds[48 + tid];
    }
}

// ---------------------------------------------------------------------------
// Kernel 4: out = elu( (sum of 4 numerator slabs) / (sum of 4 l slabs) )
__global__ __launch_bounds__(256) void gat_final(
    const float* __restrict__ pOut, const float* __restrict__ lPart,
    float* __restrict__ out)
{
    const int idx = blockIdx.x * 256 + threadIdx.x;
    const int row = idx >> 6;
    const float v = pOut[idx] + pOut[524288 + idx] + pOut[1048576 + idx]
                  + pOut[1572864 + idx];
    const float l = lPart[row] + lPart[8192 + row] + lPart[16384 + row]
                  + lPart[24576 + row];
    const float r = v / l;
    out[idx] = r > 0.f ? r : (__builtin_amdgcn_exp2f(r * LOG2E) - 1.0f);
}

extern "C" void kernel_launch(void* const* d_in, const int* in_sizes, int n_in,
                              void* d_out, int out_size, void* d_ws, size_t ws_size,
                              hipStream_t stream) {
    const float* input = (const float*)d_in[0];   // 8192 x 512 f32
    const int*   adj   = (const int*)d_in[1];     // 8192 x 8192 i32
    const float* W     = (const float*)d_in[2];   // 512 x 64 f32
    const float* a     = (const float*)d_in[3];   // 128 x 1 f32
    float* out = (float*)d_out;                   // 8192 x 64 f32

    char* ws = (char*)d_ws;
    unsigned*       wsR   = (unsigned*)(ws + 0);             // 4 B   [zeroed]
    float*          attL  = (float*)(ws + 4096);             // 32 KB
    float*          ERt   = (float*)(ws + 36864);            // 32 KB exp(attR)
    float*          ER2t  = (float*)(ws + 69632);            // 32 KB exp(0.2*attR)
    float*          lPart = (float*)(ws + 102400);           // 128 KB (4 slabs)
    unsigned short* hPack = (unsigned short*)(ws + 262144);  // 1 MB fragment-major h^T
    float*          hPart = (float*)(ws + 2097152);          // 8 MB (4 k-split slabs)
    float*          pOut  = (float*)(ws + 10485760);         // 8 MB (4 q4 slabs)
    unsigned*       adjU  = (unsigned*)(ws + 18874368);      // 8 MB linear bitmask

    hipMemsetAsync(d_ws, 0, 64, stream);   // wsR only — everything else fully written

    gat_pack <<<8192, 256, 0, stream>>>(adj, adjU);
    gat_h    <<<2048, 256, 0, stream>>>(input, W, hPart);
    gat_aux  <<< 256, 256, 0, stream>>>(hPart, a, attL, ERt, ER2t, hPack, wsR);
    gat_attn <<<2048, 256, 0, stream>>>(adjU, attL, ERt, ER2t, hPack, wsR, pOut, lPart);
    gat_final<<<2048, 256, 0, stream>>>(pOut, lPart, out);
}

// Round 8
// 422.044 us; speedup vs baseline: 1.2067x; 1.2067x over previous
//
#include <hip/hip_runtime.h>
#include <stdint.h>

#define ALPHA 0.2f
#define LOG2E 1.44269504088896340736f

typedef __attribute__((ext_vector_type(8))) short bf16x8;
typedef __attribute__((ext_vector_type(4))) float f32x4;

__device__ __forceinline__ unsigned short f2bf(float f) {
    unsigned u = __builtin_bit_cast(unsigned, f);
    u += 0x7fffu + ((u >> 16) & 1u);
    return (unsigned short)(u >> 16);
}
__device__ __forceinline__ float bf2f(unsigned short h) {
    unsigned u = ((unsigned)h) << 16;
    return __builtin_bit_cast(float, u);
}
// order-preserving float<->uint for atomicMax over signed floats (0 = -inf identity)
__device__ __forceinline__ unsigned f2ord(float f) {
    unsigned b = __builtin_bit_cast(unsigned, f);
    return (b & 0x80000000u) ? ~b : (b | 0x80000000u);
}
__device__ __forceinline__ float ord2f(unsigned k) {
    unsigned b = (k & 0x80000000u) ? (k & 0x7fffffffu) : ~k;
    return __builtin_bit_cast(float, b);
}

// ---------------------------------------------------------------------------
// Kernel 1: h = input @ W, fp32, k-split x4 with fp32 atomic accumulation.
__global__ __launch_bounds__(256) void gat_h(
    const float* __restrict__ input, const float* __restrict__ W,
    float* __restrict__ h)
{
    __shared__ float x_lds[16 * 128];
    const int tid = threadIdx.x;
    const int i0  = (blockIdx.x >> 2) * 16;
    const int k0  = (blockIdx.x & 3) * 128;

    {
        const int r  = tid >> 4;
        const int jc = (tid & 15) * 8;
        const float* src = input + (size_t)(i0 + r) * 512 + k0 + jc;
        *(f32x4*)&x_lds[r * 128 + jc]     = *(const f32x4*)src;
        *(f32x4*)&x_lds[r * 128 + jc + 4] = *(const f32x4*)(src + 4);
    }
    __syncthreads();

    const int c = tid & 63;
    const int w = tid >> 6;
    float acc[4] = {0.f, 0.f, 0.f, 0.f};
    const float* Wc = W + (size_t)k0 * 64 + c;
    #pragma unroll 4
    for (int kk = 0; kk < 128; kk += 4) {
        const float w0 = Wc[(kk+0)*64], w1 = Wc[(kk+1)*64];
        const float w2 = Wc[(kk+2)*64], w3 = Wc[(kk+3)*64];
        #pragma unroll
        for (int ri = 0; ri < 4; ++ri) {
            const f32x4 x = *(const f32x4*)&x_lds[(w + 4*ri) * 128 + kk];
            acc[ri] += x.x * w0 + x.y * w1 + x.z * w2 + x.w * w3;
        }
    }
    #pragma unroll
    for (int ri = 0; ri < 4; ++ri)
        unsafeAtomicAdd(&h[(size_t)(i0 + w + 4*ri) * 64 + c], acc[ri]);
}

// ---------------------------------------------------------------------------
// Kernel 2: attL/attR, R = max(attR), hPack (MFMA-B-fragment-major bf16 h^T).
__global__ __launch_bounds__(256) void gat_aux(
    const float* __restrict__ h, const float* __restrict__ a,
    float* __restrict__ attL, float* __restrict__ attR,
    unsigned short* __restrict__ hPack, unsigned* __restrict__ wsR)
{
    __shared__ float hl[32 * 64];
    __shared__ unsigned rmax;
    const int tid = threadIdx.x;
    const int j0  = blockIdx.x * 32;
    if (tid == 0) rmax = 0u;

    {
        const float* src = h + (size_t)j0 * 64 + tid * 8;
        *(f32x4*)&hl[tid * 8]     = *(const f32x4*)src;
        *(f32x4*)&hl[tid * 8 + 4] = *(const f32x4*)(src + 4);
    }
    __syncthreads();

    {
        const int row = tid >> 3;
        const int cs  = (tid & 7) * 8;
        float pL = 0.f, pR = 0.f;
        #pragma unroll
        for (int u = 0; u < 8; ++u) {
            const float hv = hl[row * 64 + cs + u];
            pL += hv * a[cs + u];
            pR += hv * a[64 + cs + u];
        }
        pL += __shfl_xor(pL, 1, 64); pR += __shfl_xor(pR, 1, 64);
        pL += __shfl_xor(pL, 2, 64); pR += __shfl_xor(pR, 2, 64);
        pL += __shfl_xor(pL, 4, 64); pR += __shfl_xor(pR, 4, 64);
        if ((tid & 7) == 0) {
            attL[j0 + row] = pL;
            attR[j0 + row] = pR;
            atomicMax(&rmax, f2ord(pR));
        }
    }

    {
        const int g = tid >> 6;
        const int l = tid & 63;
        const int m = l & 15;
        const int q = l >> 4;
        bf16x8 v;
        #pragma unroll
        for (int u = 0; u < 8; ++u)
            v[u] = (short)f2bf(hl[(q * 8 + u) * 64 + g * 16 + m]);
        *(bf16x8*)&hPack[(size_t)(blockIdx.x * 4 + g) * 512 + l * 8] = v;
    }

    __syncthreads();
    if (tid == 0) atomicMax(wsR, rmax);
}

// ---------------------------------------------------------------------------
// Kernel 3 (FUSED pack+attn, R5 structure): phase 1 packs raw adj -> LDS
// bitmask with EXPLICIT 8-deep load batches (8 independent int4s in flight
// before any dependent pack/store) + shift-add pack (adj in {0,1});
// phase 2 identical to the 415 us R5 kernel (in-loop exp, atomics out).
__global__ __launch_bounds__(256, 8) void gat_attn(
    const int* __restrict__ adj,
    const float* __restrict__ attL, const float* __restrict__ attR,
    const unsigned short* __restrict__ hPack, const unsigned* __restrict__ wsR,
    float* __restrict__ outAcc, float* __restrict__ lAcc)
{
    __shared__ unsigned smem[4096];   // phase1: bitmask; phase2 epilogue: acc floats
    __shared__ float l_lds[64];
    const int tid  = threadIdx.x;
    const int lane = tid & 63;
    const int wq   = tid >> 6;
    const int m    = lane & 15;
    const int quad = lane >> 4;
    const int ti   = blockIdx.x >> 2;
    const int q4   = blockIdx.x & 3;
    const int i0   = ti * 16;
    const int jc0  = q4 * 64 + wq * 16;

    // ---- phase 1: pack adj[i0..i0+16)[q4*2048..+2048) -> LDS bitmask ----
    {
        const int r    = tid >> 4;
        const int lidx = (tid & 3) * 16 + r;
        const int t    = (tid & 15) >> 2;
        unsigned char* bb = (unsigned char*)smem;
        const int* src = adj + (size_t)(i0 + r) * 8192 + q4 * 2048 + (tid & 15) * 8;
        #pragma unroll
        for (int qtr = 0; qtr < 4; ++qtr) {
            int4 va[4], vb[4];
            #pragma unroll
            for (int b = 0; b < 4; ++b) {          // 8 independent loads first
                va[b] = *(const int4*)(src + (qtr * 4 + b) * 128);
                vb[b] = *(const int4*)(src + (qtr * 4 + b) * 128 + 4);
            }
            #pragma unroll
            for (int b = 0; b < 4; ++b) {          // then the dependent packs
                const int it = qtr * 4 + b;
                const unsigned byt = (unsigned)va[b].x + ((unsigned)va[b].y << 1)
                                   + ((unsigned)va[b].z << 2) + ((unsigned)va[b].w << 3)
                                   + ((unsigned)vb[b].x << 4) + ((unsigned)vb[b].y << 5)
                                   + ((unsigned)vb[b].z << 6) + ((unsigned)vb[b].w << 7);
                bb[((((it >> 2) * 1024) + (it & 3) * 64 + lidx) << 2) + t] =
                    (unsigned char)byt;
            }
        }
    }
    __syncthreads();

    unsigned abw[4];
    #pragma unroll
    for (int g4 = 0; g4 < 4; ++g4)
        abw[g4] = smem[wq * 1024 + g4 * 64 + lane];

    const float R   = ord2f(*wsR);
    const float a_l = attL[i0 + m];
    const float t0  = a_l + R;
    const float M   = fmaxf(t0, ALPHA * t0);   // row upper bound (lrelu monotone)
    const float mc  = M * LOG2E;

    const float*          ar_p = attR + jc0 * 32 + quad * 8;
    const unsigned short* hp_p = hPack + (size_t)jc0 * 4 * 512 + lane * 8;

    f32x4 acc[4];
    #pragma unroll
    for (int g = 0; g < 4; ++g) acc[g] = (f32x4){0.f, 0.f, 0.f, 0.f};
    float lsum = 0.f;

    #pragma unroll
    for (int jg = 0; jg < 4; ++jg) {
        const unsigned ab = abw[jg];
        #pragma unroll
        for (int t = 0; t < 4; ++t) {
            const int s = jg * 4 + t;
            const f32x4 r0 = *(const f32x4*)(ar_p + s * 32);
            const f32x4 r1 = *(const f32x4*)(ar_p + s * 32 + 4);
            bf16x8 B[4];
            #pragma unroll
            for (int g = 0; g < 4; ++g)
                B[g] = *(const bf16x8*)(hp_p + (size_t)(s * 4 + g) * 512);

            const unsigned bits = (ab >> (t * 8)) & 0xffu;
            const float tv[8] = { a_l + r0.x, a_l + r0.y, a_l + r0.z, a_l + r0.w,
                                  a_l + r1.x, a_l + r1.y, a_l + r1.z, a_l + r1.w };
            bf16x8 af;
            #pragma unroll
            for (int u = 0; u < 8; ++u) {
                const float e  = fmaxf(tv[u], ALPHA * tv[u]);        // leaky_relu
                const float pe = __builtin_amdgcn_exp2f(__builtin_fmaf(e, LOG2E, -mc));
                const float pv = (bits & (1u << u)) ? pe : 0.0f;     // mask
                const unsigned short pb = f2bf(pv);
                af[u] = (short)pb;
                lsum += bf2f(pb);   // denominator from the SAME rounded weights
            }
            #pragma unroll
            for (int g = 0; g < 4; ++g)
                acc[g] = __builtin_amdgcn_mfma_f32_16x16x32_bf16(af, B[g], acc[g], 0, 0, 0);
        }
    }

    // reduce l across the 4 k-quads (row m lives in lanes m, m+16, m+32, m+48)
    lsum += __shfl_xor(lsum, 16, 64);
    lsum += __shfl_xor(lsum, 32, 64);
    if (lane < 16) l_lds[wq * 16 + lane] = lsum;
    float* accf = (float*)smem;   // wave wq overwrites its own aliased 1 KB region
    #pragma unroll
    for (int g = 0; g < 4; ++g)
        *(f32x4*)&accf[(wq * 64 + lane) * 16 + g * 4] = acc[g];
    __syncthreads();

    // combine 4 waves, scatter partial numerator to global accumulator
    #pragma unroll
    for (int q = 0; q < 4; ++q) {
        const int e      = tid + q * 256;
        const int lane_e = e >> 4;
        const int k16    = e & 15;
        float s = 0.f;
        #pragma unroll
        for (int ww = 0; ww < 4; ++ww) s += accf[(ww * 64 + lane_e) * 16 + k16];
        const int row = (lane_e >> 4) * 4 + (k16 & 3);   // C/D: row = quad*4+reg
        const int col = (k16 >> 2) * 16 + (lane_e & 15); // C/D: col = lane&15 per n-group
        unsafeAtomicAdd(&outAcc[(size_t)(i0 + row) * 64 + col], s);
    }
    if (tid < 16) {
        const float s = l_lds[tid] + l_lds[16 + tid] + l_lds[32 + tid] + l_lds[48 + tid];
        unsafeAtomicAdd(&lAcc[i0 + tid], s);
    }
}

// ---------------------------------------------------------------------------
// Kernel 4: out = elu(numerator / denominator), in place
__global__ __launch_bounds__(256) void gat_final(
    float* __restrict__ out, const float* __restrict__ lAcc)
{
    const int idx = blockIdx.x * 256 + threadIdx.x;
    const float v = out[idx] / lAcc[idx >> 6];
    out[idx] = v > 0.f ? v : (__builtin_amdgcn_exp2f(v * LOG2E) - 1.0f);
}

extern "C" void kernel_launch(void* const* d_in, const int* in_sizes, int n_in,
                              void* d_out, int out_size, void* d_ws, size_t ws_size,
                              hipStream_t stream) {
    const float* input = (const float*)d_in[0];   // 8192 x 512 f32
    const int*   adj   = (const int*)d_in[1];     // 8192 x 8192 i32
    const float* W     = (const float*)d_in[2];   // 512 x 64 f32
    const float* a     = (const float*)d_in[3];   // 128 x 1 f32
    float* out = (float*)d_out;                   // 8192 x 64 f32

    char* ws = (char*)d_ws;
    unsigned*       wsR   = (unsigned*)(ws + 0);            // 4 B    [zeroed]
    float*          lAcc  = (float*)(ws + 4096);            // 32 KB  [zeroed]
    float*          h     = (float*)(ws + 36864);           // 2 MB   [zeroed]
    float*          attL  = (float*)(ws + 2134016);         // 32 KB
    float*          attR  = (float*)(ws + 2166784);         // 32 KB
    unsigned short* hPack = (unsigned short*)(ws + 2199552);// 1 MB   fragment-major h^T bf16

    hipMemsetAsync(d_out, 0, (size_t)out_size * sizeof(float), stream);
    hipMemsetAsync(d_ws, 0, 2134016, stream);   // wsR + lAcc + h

    gat_h    <<<2048, 256, 0, stream>>>(input, W, h);
    gat_aux  <<< 256, 256, 0, stream>>>(h, a, attL, attR, hPack, wsR);
    gat_attn <<<2048, 256, 0, stream>>>(adj, attL, attR, hPack, wsR, out, lAcc);
    gat_final<<<2048, 256, 0, stream>>>(out, lAcc);
}